// Round 1
// baseline (941.897 us; speedup 1.0000x reference)
//
#include <hip/hip_runtime.h>
#include <hip/hip_bf16.h>

#define DEV __device__ __forceinline__

typedef short bf16x8 __attribute__((ext_vector_type(8)));
typedef float f32x4 __attribute__((ext_vector_type(4)));

static constexpr int B_  = 4;
static constexpr int S_  = 1024;
static constexpr int H_  = 1024;
static constexpr int NH_ = 16;
static constexpr int DH_ = 64;
static constexpr int BS_ = B_ * S_;   // 4096
static constexpr int H3_ = 3 * H_;    // 3072

// ---------------- async global->LDS (16B per lane) ----------------
DEV void gld16(const void* g, void* l) {
  __builtin_amdgcn_global_load_lds(
      (__attribute__((address_space(1))) void*)(unsigned long long)g,
      (__attribute__((address_space(3))) void*)(unsigned)(unsigned long long)l,
      16, 0, 0);
}

// ---------------- reductions (blockDim == 256) ----------------
DEV float wred_sum(float v) {
#pragma unroll
  for (int o = 32; o; o >>= 1) v += __shfl_xor(v, o);
  return v;
}
DEV float bred_sum(float v, float* sh) {
  v = wred_sum(v);
  const int tid = threadIdx.x;
  if ((tid & 63) == 0) sh[tid >> 6] = v;
  __syncthreads();
  v = sh[0] + sh[1] + sh[2] + sh[3];
  __syncthreads();
  return v;
}
DEV float bred_max(float v, float* sh) {
#pragma unroll
  for (int o = 32; o; o >>= 1) v = fmaxf(v, __shfl_xor(v, o));
  const int tid = threadIdx.x;
  if ((tid & 63) == 0) sh[tid >> 6] = v;
  __syncthreads();
  v = fmaxf(fmaxf(sh[0], sh[1]), fmaxf(sh[2], sh[3]));
  __syncthreads();
  return v;
}
DEV float geluf(float x) { return 0.5f * x * (1.f + erff(x * 0.70710678118654752f)); }

// ---------------- casts ----------------
__global__ __launch_bounds__(256) void cast_k(const float* __restrict__ in,
                                              __hip_bfloat16* __restrict__ out, int n) {
  int i = blockIdx.x * 256 + threadIdx.x;
  if (i < n) out[i] = __float2bfloat16(in[i]);
}
__global__ __launch_bounds__(256) void cast_pad_k(const float* __restrict__ in,
                                                  __hip_bfloat16* __restrict__ out,
                                                  int nsrc, int ntot) {
  int i = blockIdx.x * 256 + threadIdx.x;
  if (i < ntot) out[i] = __float2bfloat16(i < nsrc ? in[i] : 0.f);
}

// ---------------- MFMA GEMM: C[M,N] = A[M,K] * W[N,K]^T ----------------
// m97-style: 256 threads (WR x WC waves, each wave MT*16 x NT*16), BK=32,
// global_load_lds width-16 staging, single-buffer 2-barrier K loop.
template <int MT, int NT, int WR, int WC, bool OBF>
__global__ __launch_bounds__(256) void gemm_bt(
    const __hip_bfloat16* __restrict__ Ap, const __hip_bfloat16* __restrict__ Wp,
    void* __restrict__ Cp, int K, int lda, int ldw, int ldc,
    long long szA, long long szW, long long szC) {
  constexpr int BM = WR * MT * 16;
  constexpr int BN = WC * NT * 16;
  constexpr int BK = 32;
  __shared__ __align__(16) short sA[BM * BK];
  __shared__ __align__(16) short sB[BN * BK];
  const int tid = threadIdx.x;
  const int wave = tid >> 6, lane = tid & 63;
  const int wm = wave / WC, wn = wave % WC;
  const int lr = lane & 15, kq = lane >> 4;
  const short* Ab = (const short*)Ap + blockIdx.z * szA + (long long)blockIdx.y * BM * lda;
  const short* Wb = (const short*)Wp + blockIdx.z * szW + (long long)blockIdx.x * BN * ldw;

  f32x4 acc[MT][NT];
#pragma unroll
  for (int i = 0; i < MT; i++)
#pragma unroll
    for (int j = 0; j < NT; j++) acc[i][j] = f32x4{0.f, 0.f, 0.f, 0.f};

  for (int k0 = 0; k0 < K; k0 += BK) {
#pragma unroll
    for (int r = 0; r < BM / 64; r++) {
      int idx = r * 256 + tid;
      const short* src = Ab + (long long)(idx >> 2) * lda + k0 + (idx & 3) * 8;
      gld16(src, sA + (size_t)idx * 8);
    }
#pragma unroll
    for (int r = 0; r < BN / 64; r++) {
      int idx = r * 256 + tid;
      const short* src = Wb + (long long)(idx >> 2) * ldw + k0 + (idx & 3) * 8;
      gld16(src, sB + (size_t)idx * 8);
    }
    __syncthreads();
    bf16x8 af[MT], bfr[NT];
#pragma unroll
    for (int i = 0; i < MT; i++)
      af[i] = *(const bf16x8*)(sA + (wm * MT * 16 + i * 16 + lr) * BK + kq * 8);
#pragma unroll
    for (int j = 0; j < NT; j++)
      bfr[j] = *(const bf16x8*)(sB + (wn * NT * 16 + j * 16 + lr) * BK + kq * 8);
#pragma unroll
    for (int i = 0; i < MT; i++)
#pragma unroll
      for (int j = 0; j < NT; j++)
        acc[i][j] = __builtin_amdgcn_mfma_f32_16x16x32_bf16(af[i], bfr[j], acc[i][j], 0, 0, 0);
    __syncthreads();
  }
  const long long row0 = (long long)blockIdx.y * BM + wm * MT * 16 + kq * 4;
  const long long col0 = (long long)blockIdx.x * BN + wn * NT * 16 + lr;
  const long long cb = blockIdx.z * szC;
#pragma unroll
  for (int i = 0; i < MT; i++)
#pragma unroll
    for (int j = 0; j < NT; j++)
#pragma unroll
      for (int r = 0; r < 4; r++) {
        long long off = cb + (row0 + i * 16 + r) * ldc + col0 + j * 16;
        if constexpr (OBF)
          ((__hip_bfloat16*)Cp)[off] = __float2bfloat16(acc[i][j][r]);
        else
          ((float*)Cp)[off] = acc[i][j][r];
      }
}

// ---------------- V transpose per head: vt[bh][d][s] = v[b,s,h*64+d] ----------------
__global__ __launch_bounds__(256) void transpose_v_k(const __hip_bfloat16* __restrict__ qkv,
                                                     __hip_bfloat16* __restrict__ vt) {
  const int bh = blockIdx.y;
  const int b = bh >> 4, h = bh & 15;
  const int s0 = blockIdx.x << 6;
  __shared__ __hip_bfloat16 tile[64 * 65];
  const int tid = threadIdx.x;
  const __hip_bfloat16* src = qkv + ((size_t)(b * S_) + s0) * H3_ + 2 * H_ + h * DH_;
#pragma unroll
  for (int i = 0; i < 16; i++) {
    int idx = tid + i * 256;
    int rr = idx >> 6, cc = idx & 63;
    tile[cc * 65 + rr] = src[(size_t)rr * H3_ + cc];
  }
  __syncthreads();
  __hip_bfloat16* dst = vt + (size_t)bh * DH_ * S_ + s0;
#pragma unroll
  for (int i = 0; i < 16; i++) {
    int idx = tid + i * 256;
    int dd = idx >> 6, ss = idx & 63;
    dst[(size_t)dd * S_ + ss] = tile[dd * 65 + ss];
  }
}

// ---------------- softmax over a score row; writes bf16 probs aliased onto the row ----------------
__global__ __launch_bounds__(256) void softmax_k(float* __restrict__ sc, float scale,
                                                 const float* __restrict__ twn, int bh0) {
  __shared__ float sh[4];
  const int row = blockIdx.x;
  const int hl = row >> 10, q = row & 1023;
  float f = scale;
  if (twn) f *= twn[((bh0 + hl) >> 4) * S_ + q];
  float* r = sc + (size_t)row * S_;
  const int tid = threadIdx.x;
  float v[4];
#pragma unroll
  for (int i = 0; i < 4; i++) v[i] = r[tid + i * 256] * f;
  float m = fmaxf(fmaxf(v[0], v[1]), fmaxf(v[2], v[3]));
  m = bred_max(m, sh);
  float e[4], s = 0.f;
#pragma unroll
  for (int i = 0; i < 4; i++) { e[i] = __expf(v[i] - m); s += e[i]; }
  s = bred_sum(s, sh);
  const float inv = 1.f / s;
  __hip_bfloat16* p = (__hip_bfloat16*)r;  // all reads of r are done (sync inside reductions)
#pragma unroll
  for (int i = 0; i < 4; i++) p[tid + i * 256] = __float2bfloat16(e[i] * inv);
}

// ---------------- ttm: LN over 16 + sigmoid + affine -> T0 ----------------
__global__ __launch_bounds__(256) void ttm_temp_k(const float* __restrict__ wtp,
                                                  const float* __restrict__ g,
                                                  const float* __restrict__ be,
                                                  float* __restrict__ T0) {
  const int bs = blockIdx.x * 256 + threadIdx.x;
  const float* y = wtp + (size_t)bs * 128;
  float v[16], m = 0.f;
#pragma unroll
  for (int n = 0; n < 16; n++) { v[n] = y[n]; m += v[n]; }
  m *= (1.f / 16.f);
  float var = 0.f;
#pragma unroll
  for (int n = 0; n < 16; n++) { float d = v[n] - m; var += d * d; }
  var *= (1.f / 16.f);
  const float rs = rsqrtf(var + 1e-5f);
#pragma unroll
  for (int n = 0; n < 16; n++) {
    float z = (v[n] - m) * rs * g[n] + be[n];
    float t = 1.f / (1.f + expf(-z));
    T0[(size_t)bs * 16 + n] = 1.f + 0.1f * (t - 0.5f);
  }
}

// ---------------- thp: sigmoid(gelu(LN(T0 @ thp_w^T + b))) ----------------
__global__ __launch_bounds__(256) void thp_k(const float* __restrict__ T0,
                                             const float* __restrict__ w,
                                             const float* __restrict__ bb,
                                             const float* __restrict__ g,
                                             const float* __restrict__ be,
                                             __hip_bfloat16* __restrict__ Tb,
                                             float* __restrict__ t0out) {
  __shared__ float sh[4];
  __shared__ float t0s[16];
  const int bs = blockIdx.x, tid = threadIdx.x;
  if (tid < 16) t0s[tid] = T0[(size_t)bs * 16 + tid];
  __syncthreads();
  float y[4];
#pragma unroll
  for (int i = 0; i < 4; i++) {
    int hh = tid + i * 256;
    const float* wr = w + (size_t)hh * 16;
    float a = bb[hh];
#pragma unroll
    for (int n = 0; n < 16; n++) a += t0s[n] * wr[n];
    y[i] = a;
  }
  float mean = bred_sum(y[0] + y[1] + y[2] + y[3], sh) * (1.f / 1024.f);
  float q = 0.f;
#pragma unroll
  for (int i = 0; i < 4; i++) { float d = y[i] - mean; q += d * d; }
  float var = bred_sum(q, sh) * (1.f / 1024.f);
  const float rs = rsqrtf(var + 1e-5f);
#pragma unroll
  for (int i = 0; i < 4; i++) {
    int hh = tid + i * 256;
    float z = (y[i] - mean) * rs * g[hh] + be[hh];
    float t = 1.f / (1.f + expf(-geluf(z)));
    Tb[(size_t)bs * H_ + hh] = __float2bfloat16(t);
    if (hh == 0) t0out[bs] = t;
  }
}

// ---------------- rowsum of W1b (fp32 exact) ----------------
__global__ __launch_bounds__(256) void rowsum_k(const float* __restrict__ w1,
                                                float* __restrict__ rs) {
  const int tid = threadIdx.x;
  const int row = blockIdx.x * 4 + (tid >> 6);
  const int lane = tid & 63;
  float s = 0.f;
#pragma unroll
  for (int j = 0; j < 16; j++) s += w1[(size_t)row * 2048 + 1024 + lane + j * 64];
  s = wred_sum(s);
  if (lane == 0) rs[row] = s;
}

// ---------------- h = gelu(LN(xw1a + addend + b1)) ; hout may alias addm ----------------
__global__ __launch_bounds__(256) void hln_k(const float* __restrict__ xa,
                                             const float* __restrict__ addm,
                                             const float* __restrict__ Ti,
                                             const float* __restrict__ rsum,
                                             const float* __restrict__ b1,
                                             const float* __restrict__ g,
                                             const float* __restrict__ be,
                                             float* __restrict__ hout, int mode) {
  __shared__ float sh[4];
  const int bs = blockIdx.x, tid = threadIdx.x;
  const float tv = mode ? Ti[bs] : 0.f;
  float y[4];
#pragma unroll
  for (int i = 0; i < 4; i++) {
    int hh = tid + i * 256;
    float add = mode ? tv * rsum[hh] : addm[(size_t)bs * H_ + hh];
    y[i] = xa[(size_t)bs * H_ + hh] + add + b1[hh];
  }
  float mean = bred_sum(y[0] + y[1] + y[2] + y[3], sh) * (1.f / 1024.f);
  float q = 0.f;
#pragma unroll
  for (int i = 0; i < 4; i++) { float d = y[i] - mean; q += d * d; }
  float var = bred_sum(q, sh) * (1.f / 1024.f);
  const float rs = rsqrtf(var + 1e-5f);
#pragma unroll
  for (int i = 0; i < 4; i++) {
    int hh = tid + i * 256;
    float z = (y[i] - mean) * rs * g[hh] + be[hh];
    hout[(size_t)bs * H_ + hh] = geluf(z);
  }
}

// ---------------- Ti = sigmoid(sigmoid(h . w2 + b2)) ----------------
__global__ __launch_bounds__(256) void rowdot_k(const float* __restrict__ h,
                                                const float* __restrict__ w2,
                                                const float* __restrict__ b2,
                                                float* __restrict__ tout) {
  __shared__ float sh[4];
  const int bs = blockIdx.x, tid = threadIdx.x;
  float s = 0.f;
#pragma unroll
  for (int i = 0; i < 4; i++) {
    int hh = tid + i * 256;
    s += h[(size_t)bs * H_ + hh] * w2[hh];
  }
  s = bred_sum(s, sh);
  if (tid == 0) {
    float d = s + b2[0];
    float t = 1.f / (1.f + expf(-d));
    t = 1.f / (1.f + expf(-t));
    tout[bs] = t;
  }
}

// ---------------- global stats -> twn; also emits scale_temps output ----------------
__global__ __launch_bounds__(256) void stats_k(const float* __restrict__ t0,
                                               const float* __restrict__ t1,
                                               const float* __restrict__ t2,
                                               float* __restrict__ twn,
                                               float* __restrict__ out2) {
  __shared__ float sh[4];
  const int tid = threadIdx.x;
  float s = 0.f;
  for (int i = tid; i < BS_; i += 256) s += (t0[i] + t1[i] + t2[i]) * (1.f / 3.f);
  const float mu = bred_sum(s, sh) * (1.f / (float)BS_);
  float q = 0.f;
  for (int i = tid; i < BS_; i += 256) {
    float tw = (t0[i] + t1[i] + t2[i]) * (1.f / 3.f);
    float d = tw - mu;
    q += d * d;
  }
  const float var = bred_sum(q, sh) * (1.f / (float)BS_);
  // unbiased factor Nt/(Nt-1) with Nt=67108864 rounds to 1.0f in fp32
  const float stdu = sqrtf(var);
  const float inv = 1.f / (stdu + 1.1920929e-07f);
  for (int i = tid; i < BS_; i += 256) {
    float tw = (t0[i] + t1[i] + t2[i]) * (1.f / 3.f);
    twn[i] = 1.f + (tw - mu) * inv;
  }
  for (int i = tid; i < 3 * BS_; i += 256) {  // [B,3,S,1]
    int b = i / 3072, r = i - b * 3072;
    int j = r >> 10, ss = r & 1023;
    const float* tp = (j == 0) ? t0 : ((j == 1) ? t1 : t2);
    out2[i] = tp[b * S_ + ss];
  }
}

// =====================================================================
extern "C" void kernel_launch(void* const* d_in, const int* in_sizes, int n_in,
                              void* d_out, int out_size, void* d_ws, size_t ws_size,
                              hipStream_t stream) {
  (void)in_sizes; (void)n_in; (void)out_size;
  const float* x     = (const float*)d_in[0];
  const float* wq    = (const float*)d_in[1];
  const float* wk    = (const float*)d_in[2];
  const float* wv    = (const float*)d_in[3];
  const float* wo    = (const float*)d_in[4];
  const float* w_in  = (const float*)d_in[5];
  const float* w_out = (const float*)d_in[6];
  const float* wt    = (const float*)d_in[7];
  const float* ttm_g = (const float*)d_in[8];
  const float* ttm_b = (const float*)d_in[9];
  const float* thp_w = (const float*)d_in[10];
  const float* thp_b = (const float*)d_in[11];
  const float* thp_g = (const float*)d_in[12];
  const float* thp_e = (const float*)d_in[13];
  const float* w1    = (const float*)d_in[14];
  const float* b1    = (const float*)d_in[15];
  const float* tn_g  = (const float*)d_in[16];
  const float* tn_e  = (const float*)d_in[17];
  const float* w2    = (const float*)d_in[18];
  const float* b2    = (const float*)d_in[19];

  char* ws = (char*)d_ws;
  size_t off = 0;
  auto alloc = [&](size_t bytes) {
    void* p = ws + off;
    off = (off + bytes + 255) & ~(size_t)255;
    return p;
  };

  __hip_bfloat16* xb    = (__hip_bfloat16*)alloc((size_t)BS_ * H_ * 2);
  __hip_bfloat16* winb  = (__hip_bfloat16*)alloc((size_t)H3_ * H_ * 2);
  __hip_bfloat16* woutb = (__hip_bfloat16*)alloc((size_t)H_ * H_ * 2);
  __hip_bfloat16* wqb   = (__hip_bfloat16*)alloc((size_t)H_ * H_ * 2);
  __hip_bfloat16* wkb   = (__hip_bfloat16*)alloc((size_t)H_ * H_ * 2);
  __hip_bfloat16* wvb   = (__hip_bfloat16*)alloc((size_t)H_ * H_ * 2);
  __hip_bfloat16* wob   = (__hip_bfloat16*)alloc((size_t)H_ * H_ * 2);
  __hip_bfloat16* wtpb  = (__hip_bfloat16*)alloc((size_t)128 * H_ * 2);
  __hip_bfloat16* w1b   = (__hip_bfloat16*)alloc((size_t)H_ * 2 * H_ * 2);
  __hip_bfloat16* qkvb  = (__hip_bfloat16*)alloc((size_t)BS_ * H3_ * 2);
  __hip_bfloat16* vtb   = (__hip_bfloat16*)alloc((size_t)64 * DH_ * S_ * 2);
  __hip_bfloat16* mctxb = (__hip_bfloat16*)alloc((size_t)BS_ * H_ * 2);  // ttm ctx, later main ctx
  __hip_bfloat16* tob   = (__hip_bfloat16*)alloc((size_t)BS_ * H_ * 2);  // ttm_out, later T_base0
  float* wtp   = (float*)alloc((size_t)BS_ * 128 * 4);
  float* T0    = (float*)alloc((size_t)BS_ * NH_ * 4);
  float* xw1a  = (float*)alloc((size_t)BS_ * H_ * 4);
  float* tbw   = (float*)alloc((size_t)BS_ * H_ * 4);  // Tb0@W1b^T, later h
  float* temps = (float*)alloc((size_t)3 * BS_ * 4);
  float* twn   = (float*)alloc((size_t)BS_ * 4);
  float* rsum  = (float*)alloc((size_t)H_ * 4);
  int C = 16;  // heads per attention chunk (chunk always within one batch b)
  while (C > 1 && off + (size_t)C * S_ * S_ * 4 > ws_size) C >>= 1;
  float* scores = (float*)(ws + off);

  const float scale = 0.125f;  // DH^-0.5
  dim3 blk(256);

  // ---- casts ----
  cast_k<<<(BS_ * H_ + 255) / 256, blk, 0, stream>>>(x, xb, BS_ * H_);
  cast_k<<<(H3_ * H_ + 255) / 256, blk, 0, stream>>>(w_in, winb, H3_ * H_);
  cast_k<<<(H_ * H_ + 255) / 256, blk, 0, stream>>>(w_out, woutb, H_ * H_);
  cast_k<<<(H_ * H_ + 255) / 256, blk, 0, stream>>>(wq, wqb, H_ * H_);
  cast_k<<<(H_ * H_ + 255) / 256, blk, 0, stream>>>(wk, wkb, H_ * H_);
  cast_k<<<(H_ * H_ + 255) / 256, blk, 0, stream>>>(wv, wvb, H_ * H_);
  cast_k<<<(H_ * H_ + 255) / 256, blk, 0, stream>>>(wo, wob, H_ * H_);
  cast_pad_k<<<(128 * H_ + 255) / 256, blk, 0, stream>>>(wt, wtpb, NH_ * H_, 128 * H_);
  cast_k<<<(H_ * 2 * H_ + 255) / 256, blk, 0, stream>>>(w1, w1b, H_ * 2 * H_);

  // ---- ttm MHA: qkv = x @ mha_in_w^T ----
  gemm_bt<4, 4, 2, 2, true><<<dim3(H3_ / 128, BS_ / 128, 1), blk, 0, stream>>>(
      xb, winb, qkvb, H_, H_, H_, H3_, 0, 0, 0);
  transpose_v_k<<<dim3(S_ / 64, 64), blk, 0, stream>>>(qkvb, vtb);
  for (int c = 0; c < 64 / C; c++) {
    const int bh0 = c * C, b0 = bh0 >> 4, h0 = bh0 & 15;
    const __hip_bfloat16* qbase = qkvb + (size_t)b0 * S_ * H3_ + h0 * DH_;
    gemm_bt<4, 4, 2, 2, false><<<dim3(S_ / 128, S_ / 128, C), blk, 0, stream>>>(
        qbase, qbase + H_, scores, DH_, H3_, H3_, S_, DH_, DH_, (long long)S_ * S_);
    softmax_k<<<C * S_, blk, 0, stream>>>(scores, scale, (const float*)nullptr, bh0);
    gemm_bt<2, 4, 4, 1, true><<<dim3(1, S_ / 128, C), blk, 0, stream>>>(
        (const __hip_bfloat16*)scores, vtb + (size_t)bh0 * DH_ * S_,
        mctxb + (size_t)b0 * S_ * H_ + h0 * DH_,
        S_, 2 * S_, S_, H_, 2LL * S_ * S_, (long long)DH_ * S_, DH_);
  }
  // ttm out proj, wt proj (padded N=128)
  gemm_bt<4, 4, 2, 2, true><<<dim3(H_ / 128, BS_ / 128, 1), blk, 0, stream>>>(
      mctxb, woutb, tob, H_, H_, H_, H_, 0, 0, 0);
  gemm_bt<4, 4, 2, 2, false><<<dim3(1, BS_ / 128, 1), blk, 0, stream>>>(
      tob, wtpb, wtp, H_, H_, H_, 128, 0, 0, 0);
  ttm_temp_k<<<BS_ / 256, blk, 0, stream>>>(wtp, ttm_g, ttm_b, T0);
  thp_k<<<BS_, blk, 0, stream>>>(T0, thp_w, thp_b, thp_g, thp_e, tob, temps);

  // ---- temp_net (algebraic split of comb @ W1^T) ----
  gemm_bt<4, 4, 2, 2, false><<<dim3(H_ / 128, BS_ / 128, 1), blk, 0, stream>>>(
      xb, w1b, xw1a, H_, H_, 2 * H_, H_, 0, 0, 0);
  gemm_bt<4, 4, 2, 2, false><<<dim3(H_ / 128, BS_ / 128, 1), blk, 0, stream>>>(
      tob, w1b + H_, tbw, H_, H_, 2 * H_, H_, 0, 0, 0);
  rowsum_k<<<H_ / 4, blk, 0, stream>>>(w1, rsum);
  hln_k<<<BS_, blk, 0, stream>>>(xw1a, tbw, (const float*)nullptr, rsum, b1, tn_g, tn_e, tbw, 0);
  rowdot_k<<<BS_, blk, 0, stream>>>(tbw, w2, b2, temps + BS_);
  hln_k<<<BS_, blk, 0, stream>>>(xw1a, tbw, temps + BS_, rsum, b1, tn_g, tn_e, tbw, 1);
  rowdot_k<<<BS_, blk, 0, stream>>>(tbw, w2, b2, temps + 2 * BS_);
  stats_k<<<1, blk, 0, stream>>>(temps, temps + BS_, temps + 2 * BS_, twn,
                                 (float*)d_out + (size_t)BS_ * H_);

  // ---- main attention ----
  gemm_bt<4, 4, 2, 2, true><<<dim3(H_ / 128, BS_ / 128, 1), blk, 0, stream>>>(
      xb, wqb, qkvb, H_, H_, H_, H3_, 0, 0, 0);
  gemm_bt<4, 4, 2, 2, true><<<dim3(H_ / 128, BS_ / 128, 1), blk, 0, stream>>>(
      xb, wkb, qkvb + H_, H_, H_, H_, H3_, 0, 0, 0);
  gemm_bt<4, 4, 2, 2, true><<<dim3(H_ / 128, BS_ / 128, 1), blk, 0, stream>>>(
      xb, wvb, qkvb + 2 * H_, H_, H_, H_, H3_, 0, 0, 0);
  transpose_v_k<<<dim3(S_ / 64, 64), blk, 0, stream>>>(qkvb, vtb);
  for (int c = 0; c < 64 / C; c++) {
    const int bh0 = c * C, b0 = bh0 >> 4, h0 = bh0 & 15;
    const __hip_bfloat16* qbase = qkvb + (size_t)b0 * S_ * H3_ + h0 * DH_;
    gemm_bt<4, 4, 2, 2, false><<<dim3(S_ / 128, S_ / 128, C), blk, 0, stream>>>(
        qbase, qbase + H_, scores, DH_, H3_, H3_, S_, DH_, DH_, (long long)S_ * S_);
    softmax_k<<<C * S_, blk, 0, stream>>>(scores, scale, twn, bh0);
    gemm_bt<2, 4, 4, 1, true><<<dim3(1, S_ / 128, C), blk, 0, stream>>>(
        (const __hip_bfloat16*)scores, vtb + (size_t)bh0 * DH_ * S_,
        mctxb + (size_t)b0 * S_ * H_ + h0 * DH_,
        S_, 2 * S_, S_, H_, 2LL * S_ * S_, (long long)DH_ * S_, DH_);
  }
  // context = ctx @ wo^T -> d_out (fp32)
  gemm_bt<4, 4, 2, 2, false><<<dim3(H_ / 128, BS_ / 128, 1), blk, 0, stream>>>(
      mctxb, wob, (float*)d_out, H_, H_, H_, H_, 0, 0, 0);
}

// Round 2
// 560.014 us; speedup vs baseline: 1.6819x; 1.6819x over previous
//
#include <hip/hip_runtime.h>
#include <hip/hip_bf16.h>

#define DEV __device__ __forceinline__

typedef short bf16x8 __attribute__((ext_vector_type(8)));
typedef short bf16x4 __attribute__((ext_vector_type(4)));
typedef float f32x4 __attribute__((ext_vector_type(4)));

static constexpr int B_  = 4;
static constexpr int S_  = 1024;
static constexpr int H_  = 1024;
static constexpr int NH_ = 16;
static constexpr int DH_ = 64;
static constexpr int BS_ = B_ * S_;   // 4096
static constexpr int H3_ = 3 * H_;    // 3072

// ---------------- async global->LDS (16B per lane) ----------------
DEV void gld16(const void* g, void* l) {
  __builtin_amdgcn_global_load_lds(
      (__attribute__((address_space(1))) void*)(unsigned long long)g,
      (__attribute__((address_space(3))) void*)(unsigned)(unsigned long long)l,
      16, 0, 0);
}

// 16x16x16 bf16 MFMA (A-frag layout A[m=lane&15][k=quad*4+j] matches the
// C-layout of a transposed-score tile -> LDS-free P transpose in flash).
DEV f32x4 pv_mfma(bf16x4 a, bf16x4 b, f32x4 c) {
#if __has_builtin(__builtin_amdgcn_mfma_f32_16x16x16bf16_1k)
  return __builtin_amdgcn_mfma_f32_16x16x16bf16_1k(a, b, c, 0, 0, 0);
#else
  asm volatile("v_mfma_f32_16x16x16_bf16 %0, %1, %2, %0" : "+v"(c) : "v"(a), "v"(b));
  return c;
#endif
}

// ---------------- reductions (blockDim == 256) ----------------
DEV float wred_sum(float v) {
#pragma unroll
  for (int o = 32; o; o >>= 1) v += __shfl_xor(v, o);
  return v;
}
DEV float bred_sum(float v, float* sh) {
  v = wred_sum(v);
  const int tid = threadIdx.x;
  if ((tid & 63) == 0) sh[tid >> 6] = v;
  __syncthreads();
  v = sh[0] + sh[1] + sh[2] + sh[3];
  __syncthreads();
  return v;
}
DEV float geluf(float x) { return 0.5f * x * (1.f + erff(x * 0.70710678118654752f)); }

// ---------------- casts ----------------
__global__ __launch_bounds__(256) void cast_k(const float* __restrict__ in,
                                              __hip_bfloat16* __restrict__ out, int n) {
  int i = blockIdx.x * 256 + threadIdx.x;
  if (i < n) out[i] = __float2bfloat16(in[i]);
}
__global__ __launch_bounds__(256) void cast_pad_k(const float* __restrict__ in,
                                                  __hip_bfloat16* __restrict__ out,
                                                  int nsrc, int ntot) {
  int i = blockIdx.x * 256 + threadIdx.x;
  if (i < ntot) out[i] = __float2bfloat16(i < nsrc ? in[i] : 0.f);
}

// ---------------- MFMA GEMM: C[M,N] = A[M,K] * W[N,K]^T ----------------
template <int MT, int NT, int WR, int WC, bool OBF>
__global__ __launch_bounds__(256) void gemm_bt(
    const __hip_bfloat16* __restrict__ Ap, const __hip_bfloat16* __restrict__ Wp,
    void* __restrict__ Cp, int K, int lda, int ldw, int ldc,
    long long szA, long long szW, long long szC) {
  constexpr int BM = WR * MT * 16;
  constexpr int BN = WC * NT * 16;
  constexpr int BK = 32;
  __shared__ __align__(16) short sA[BM * BK];
  __shared__ __align__(16) short sB[BN * BK];
  const int tid = threadIdx.x;
  const int wave = tid >> 6, lane = tid & 63;
  const int wm = wave / WC, wn = wave % WC;
  const int lr = lane & 15, kq = lane >> 4;
  const short* Ab = (const short*)Ap + blockIdx.z * szA + (long long)blockIdx.y * BM * lda;
  const short* Wb = (const short*)Wp + blockIdx.z * szW + (long long)blockIdx.x * BN * ldw;

  f32x4 acc[MT][NT];
#pragma unroll
  for (int i = 0; i < MT; i++)
#pragma unroll
    for (int j = 0; j < NT; j++) acc[i][j] = f32x4{0.f, 0.f, 0.f, 0.f};

  for (int k0 = 0; k0 < K; k0 += BK) {
#pragma unroll
    for (int r = 0; r < BM / 64; r++) {
      int idx = r * 256 + tid;
      const short* src = Ab + (long long)(idx >> 2) * lda + k0 + (idx & 3) * 8;
      gld16(src, sA + (size_t)idx * 8);
    }
#pragma unroll
    for (int r = 0; r < BN / 64; r++) {
      int idx = r * 256 + tid;
      const short* src = Wb + (long long)(idx >> 2) * ldw + k0 + (idx & 3) * 8;
      gld16(src, sB + (size_t)idx * 8);
    }
    __syncthreads();
    bf16x8 af[MT], bfr[NT];
#pragma unroll
    for (int i = 0; i < MT; i++)
      af[i] = *(const bf16x8*)(sA + (wm * MT * 16 + i * 16 + lr) * BK + kq * 8);
#pragma unroll
    for (int j = 0; j < NT; j++)
      bfr[j] = *(const bf16x8*)(sB + (wn * NT * 16 + j * 16 + lr) * BK + kq * 8);
#pragma unroll
    for (int i = 0; i < MT; i++)
#pragma unroll
      for (int j = 0; j < NT; j++)
        acc[i][j] = __builtin_amdgcn_mfma_f32_16x16x32_bf16(af[i], bfr[j], acc[i][j], 0, 0, 0);
    __syncthreads();
  }
  const long long row0 = (long long)blockIdx.y * BM + wm * MT * 16 + kq * 4;
  const long long col0 = (long long)blockIdx.x * BN + wn * NT * 16 + lr;
  const long long cb = blockIdx.z * szC;
#pragma unroll
  for (int i = 0; i < MT; i++)
#pragma unroll
    for (int j = 0; j < NT; j++)
#pragma unroll
      for (int r = 0; r < 4; r++) {
        long long off = cb + (row0 + i * 16 + r) * ldc + col0 + j * 16;
        if constexpr (OBF)
          ((__hip_bfloat16*)Cp)[off] = __float2bfloat16(acc[i][j][r]);
        else
          ((float*)Cp)[off] = acc[i][j][r];
      }
}

// ---------------- V transpose per head: vt[bh][d][s] = v[b,s,2H + h*64+d] ----------------
__global__ __launch_bounds__(256) void transpose_v_k(const __hip_bfloat16* __restrict__ qkv,
                                                     __hip_bfloat16* __restrict__ vt) {
  const int bh = blockIdx.y;
  const int b = bh >> 4, h = bh & 15;
  const int s0 = blockIdx.x << 6;
  __shared__ __hip_bfloat16 tile[64 * 65];
  const int tid = threadIdx.x;
  const __hip_bfloat16* src = qkv + ((size_t)(b * S_) + s0) * H3_ + 2 * H_ + h * DH_;
#pragma unroll
  for (int i = 0; i < 16; i++) {
    int idx = tid + i * 256;
    int rr = idx >> 6, cc = idx & 63;
    tile[cc * 65 + rr] = src[(size_t)rr * H3_ + cc];
  }
  __syncthreads();
  __hip_bfloat16* dst = vt + (size_t)bh * DH_ * S_ + s0;
#pragma unroll
  for (int i = 0; i < 16; i++) {
    int idx = tid + i * 256;
    int dd = idx >> 6, ss = idx & 63;
    dst[(size_t)dd * S_ + ss] = tile[dd * 65 + ss];
  }
}

// ---------------- fused flash attention ----------------
// Block = (q-tile of 128, bh). 4 waves; wave w owns q columns w*32..w*32+31.
// S^T = K·Q^T via 16x16x32 mfma; online softmax over s (rows of S^T);
// P^T stays in registers (C-layout == x16 A-frag layout); O += P·V via 16x16x16.
template <bool TTM>
__global__ __launch_bounds__(256) void flash_k(
    const __hip_bfloat16* __restrict__ qkv,   // [B,S,3H]
    const __hip_bfloat16* __restrict__ vt,    // [bh][DH][S]
    const float* __restrict__ twn,            // [B*S] or unused
    __hip_bfloat16* __restrict__ ctx,         // [B,S,H]
    float scale) {
  constexpr int LQ = 72;    // padded row stride (shorts) for 64-wide rows
  constexpr int LV = 136;   // padded row stride (shorts) for 128-wide rows
  __shared__ __align__(16) short sQ[128 * LQ];
  __shared__ __align__(16) short sK[128 * LQ];
  __shared__ __align__(16) short sVT[64 * LV];
  const int bh = blockIdx.y, b = bh >> 4, h = bh & 15;
  const int qb = blockIdx.x;  // 0..7
  const int tid = threadIdx.x, lane = tid & 63, wid = tid >> 6;
  const int lr = lane & 15, quad = lane >> 4;
  const short* qg = (const short*)qkv + ((size_t)(b * S_) + qb * 128) * H3_ + h * 64;
  const short* kg = (const short*)qkv + (size_t)b * S_ * H3_ + H_ + h * 64;
  const short* vg = (const short*)vt + (size_t)bh * DH_ * S_;

  // stage Q once: 128 rows x 64 shorts = 1024 x 16B chunks
#pragma unroll
  for (int i = 0; i < 4; i++) {
    int idx = tid + i * 256, row = idx >> 3, c = idx & 7;
    *(int4*)(sQ + row * LQ + c * 8) = *(const int4*)(qg + (size_t)row * H3_ + c * 8);
  }
  float fs[2];
#pragma unroll
  for (int nt = 0; nt < 2; nt++) {
    int q = qb * 128 + wid * 32 + nt * 16 + lr;
    fs[nt] = TTM ? scale : scale * twn[b * S_ + q];
  }
  f32x4 O[2][4];
#pragma unroll
  for (int nt = 0; nt < 2; nt++)
#pragma unroll
    for (int dt = 0; dt < 4; dt++) O[nt][dt] = f32x4{0.f, 0.f, 0.f, 0.f};
  float mrow[2] = {-INFINITY, -INFINITY};
  float lrow[2] = {0.f, 0.f};

  for (int kt = 0; kt < 8; kt++) {
    __syncthreads();
#pragma unroll
    for (int i = 0; i < 4; i++) {
      int idx = tid + i * 256, row = idx >> 3, c = idx & 7;
      *(int4*)(sK + row * LQ + c * 8) =
          *(const int4*)(kg + (size_t)(kt * 128 + row) * H3_ + c * 8);
    }
#pragma unroll
    for (int i = 0; i < 4; i++) {
      int idx = tid + i * 256, row = idx >> 4, c = idx & 15;
      *(int4*)(sVT + row * LV + c * 8) =
          *(const int4*)(vg + (size_t)row * S_ + kt * 128 + c * 8);
    }
    __syncthreads();

    // ---- S^T tile: 128(s) x 32(q per wave) ----
    f32x4 Sa[8][2];
#pragma unroll
    for (int mt = 0; mt < 8; mt++)
#pragma unroll
      for (int nt = 0; nt < 2; nt++) Sa[mt][nt] = f32x4{0.f, 0.f, 0.f, 0.f};
    bf16x8 bq[2][2];
#pragma unroll
    for (int nt = 0; nt < 2; nt++)
#pragma unroll
      for (int kk = 0; kk < 2; kk++)
        bq[nt][kk] = *(const bf16x8*)(sQ + (wid * 32 + nt * 16 + lr) * LQ + kk * 32 + quad * 8);
#pragma unroll
    for (int mt = 0; mt < 8; mt++)
#pragma unroll
      for (int kk = 0; kk < 2; kk++) {
        bf16x8 ak = *(const bf16x8*)(sK + (mt * 16 + lr) * LQ + kk * 32 + quad * 8);
#pragma unroll
        for (int nt = 0; nt < 2; nt++)
          Sa[mt][nt] = __builtin_amdgcn_mfma_f32_16x16x32_bf16(ak, bq[nt][kk], Sa[mt][nt], 0, 0, 0);
      }

    // ---- online softmax per q column (col = lane&15 of tile nt) ----
    bf16x4 Pf[8][2];
#pragma unroll
    for (int nt = 0; nt < 2; nt++) {
      float mx = -INFINITY;
#pragma unroll
      for (int mt = 0; mt < 8; mt++)
#pragma unroll
        for (int r = 0; r < 4; r++) {
          Sa[mt][nt][r] *= fs[nt];
          mx = fmaxf(mx, Sa[mt][nt][r]);
        }
      mx = fmaxf(mx, __shfl_xor(mx, 16));
      mx = fmaxf(mx, __shfl_xor(mx, 32));
      const float mnew = fmaxf(mrow[nt], mx);
      const float al = __expf(mrow[nt] - mnew);
      mrow[nt] = mnew;
      float ls = 0.f;
#pragma unroll
      for (int mt = 0; mt < 8; mt++) {
        float p0 = __expf(Sa[mt][nt][0] - mnew);
        float p1 = __expf(Sa[mt][nt][1] - mnew);
        float p2 = __expf(Sa[mt][nt][2] - mnew);
        float p3 = __expf(Sa[mt][nt][3] - mnew);
        ls += (p0 + p1) + (p2 + p3);
        __hip_bfloat16 h0 = __float2bfloat16(p0), h1 = __float2bfloat16(p1);
        __hip_bfloat16 h2 = __float2bfloat16(p2), h3 = __float2bfloat16(p3);
        bf16x4 pk;
        pk[0] = *(short*)&h0; pk[1] = *(short*)&h1;
        pk[2] = *(short*)&h2; pk[3] = *(short*)&h3;
        Pf[mt][nt] = pk;
      }
      ls += __shfl_xor(ls, 16);
      ls += __shfl_xor(ls, 32);
      lrow[nt] = lrow[nt] * al + ls;
      // rescale O rows (row q' = quad*4+r holds its alpha at lane q')
#pragma unroll
      for (int r = 0; r < 4; r++) {
        float ar = __shfl(al, quad * 4 + r);
#pragma unroll
        for (int dt = 0; dt < 4; dt++) O[nt][dt][r] *= ar;
      }
    }

    // ---- O += P·V via 16x16x16 (P^T regs are A-frags directly) ----
#pragma unroll
    for (int mt = 0; mt < 8; mt++)
#pragma unroll
      for (int dt = 0; dt < 4; dt++) {
        bf16x4 bv = *(const bf16x4*)(sVT + (dt * 16 + lr) * LV + mt * 16 + quad * 4);
#pragma unroll
        for (int nt = 0; nt < 2; nt++) O[nt][dt] = pv_mfma(Pf[mt][nt], bv, O[nt][dt]);
      }
  }

  // ---- epilogue: O /= l, store ----
#pragma unroll
  for (int nt = 0; nt < 2; nt++)
#pragma unroll
    for (int r = 0; r < 4; r++) {
      float li = __shfl(lrow[nt], quad * 4 + r);
      float inv = 1.f / li;
      int q = qb * 128 + wid * 32 + nt * 16 + quad * 4 + r;
      __hip_bfloat16* op = ctx + ((size_t)(b * S_) + q) * H_ + h * 64 + lr;
#pragma unroll
      for (int dt = 0; dt < 4; dt++)
        op[dt * 16] = __float2bfloat16(O[nt][dt][r] * inv);
    }
}

// ---------------- ttm: LN over 16 + sigmoid + affine -> T0 ----------------
__global__ __launch_bounds__(256) void ttm_temp_k(const float* __restrict__ wtp,
                                                  const float* __restrict__ g,
                                                  const float* __restrict__ be,
                                                  float* __restrict__ T0) {
  const int bs = blockIdx.x * 256 + threadIdx.x;
  const float* y = wtp + (size_t)bs * 128;
  float v[16], m = 0.f;
#pragma unroll
  for (int n = 0; n < 16; n++) { v[n] = y[n]; m += v[n]; }
  m *= (1.f / 16.f);
  float var = 0.f;
#pragma unroll
  for (int n = 0; n < 16; n++) { float d = v[n] - m; var += d * d; }
  var *= (1.f / 16.f);
  const float rs = rsqrtf(var + 1e-5f);
#pragma unroll
  for (int n = 0; n < 16; n++) {
    float z = (v[n] - m) * rs * g[n] + be[n];
    float t = 1.f / (1.f + expf(-z));
    T0[(size_t)bs * 16 + n] = 1.f + 0.1f * (t - 0.5f);
  }
}

// ---------------- thp: sigmoid(gelu(LN(T0 @ thp_w^T + b))) ----------------
__global__ __launch_bounds__(256) void thp_k(const float* __restrict__ T0,
                                             const float* __restrict__ w,
                                             const float* __restrict__ bb,
                                             const float* __restrict__ g,
                                             const float* __restrict__ be,
                                             __hip_bfloat16* __restrict__ Tb,
                                             float* __restrict__ t0out) {
  __shared__ float sh[4];
  __shared__ float t0s[16];
  const int bs = blockIdx.x, tid = threadIdx.x;
  if (tid < 16) t0s[tid] = T0[(size_t)bs * 16 + tid];
  __syncthreads();
  float y[4];
#pragma unroll
  for (int i = 0; i < 4; i++) {
    int hh = tid + i * 256;
    const float* wr = w + (size_t)hh * 16;
    float a = bb[hh];
#pragma unroll
    for (int n = 0; n < 16; n++) a += t0s[n] * wr[n];
    y[i] = a;
  }
  float mean = bred_sum(y[0] + y[1] + y[2] + y[3], sh) * (1.f / 1024.f);
  float q = 0.f;
#pragma unroll
  for (int i = 0; i < 4; i++) { float d = y[i] - mean; q += d * d; }
  float var = bred_sum(q, sh) * (1.f / 1024.f);
  const float rs = rsqrtf(var + 1e-5f);
#pragma unroll
  for (int i = 0; i < 4; i++) {
    int hh = tid + i * 256;
    float z = (y[i] - mean) * rs * g[hh] + be[hh];
    float t = 1.f / (1.f + expf(-geluf(z)));
    Tb[(size_t)bs * H_ + hh] = __float2bfloat16(t);
    if (hh == 0) t0out[bs] = t;
  }
}

// ---------------- rowsum of W1b (fp32 exact) ----------------
__global__ __launch_bounds__(256) void rowsum_k(const float* __restrict__ w1,
                                                float* __restrict__ rs) {
  const int tid = threadIdx.x;
  const int row = blockIdx.x * 4 + (tid >> 6);
  const int lane = tid & 63;
  float s = 0.f;
#pragma unroll
  for (int j = 0; j < 16; j++) s += w1[(size_t)row * 2048 + 1024 + lane + j * 64];
  s = wred_sum(s);
  if (lane == 0) rs[row] = s;
}

// ---------------- h = gelu(LN(xw1a + addend + b1)) ----------------
__global__ __launch_bounds__(256) void hln_k(const float* __restrict__ xa,
                                             const float* __restrict__ addm,
                                             const float* __restrict__ Ti,
                                             const float* __restrict__ rsum,
                                             const float* __restrict__ b1,
                                             const float* __restrict__ g,
                                             const float* __restrict__ be,
                                             float* __restrict__ hout, int mode) {
  __shared__ float sh[4];
  const int bs = blockIdx.x, tid = threadIdx.x;
  const float tv = mode ? Ti[bs] : 0.f;
  float y[4];
#pragma unroll
  for (int i = 0; i < 4; i++) {
    int hh = tid + i * 256;
    float add = mode ? tv * rsum[hh] : addm[(size_t)bs * H_ + hh];
    y[i] = xa[(size_t)bs * H_ + hh] + add + b1[hh];
  }
  float mean = bred_sum(y[0] + y[1] + y[2] + y[3], sh) * (1.f / 1024.f);
  float q = 0.f;
#pragma unroll
  for (int i = 0; i < 4; i++) { float d = y[i] - mean; q += d * d; }
  float var = bred_sum(q, sh) * (1.f / 1024.f);
  const float rs = rsqrtf(var + 1e-5f);
#pragma unroll
  for (int i = 0; i < 4; i++) {
    int hh = tid + i * 256;
    float z = (y[i] - mean) * rs * g[hh] + be[hh];
    hout[(size_t)bs * H_ + hh] = geluf(z);
  }
}

// ---------------- Ti = sigmoid(sigmoid(h . w2 + b2)) ----------------
__global__ __launch_bounds__(256) void rowdot_k(const float* __restrict__ h,
                                                const float* __restrict__ w2,
                                                const float* __restrict__ b2,
                                                float* __restrict__ tout) {
  __shared__ float sh[4];
  const int bs = blockIdx.x, tid = threadIdx.x;
  float s = 0.f;
#pragma unroll
  for (int i = 0; i < 4; i++) {
    int hh = tid + i * 256;
    s += h[(size_t)bs * H_ + hh] * w2[hh];
  }
  s = bred_sum(s, sh);
  if (tid == 0) {
    float d = s + b2[0];
    float t = 1.f / (1.f + expf(-d));
    t = 1.f / (1.f + expf(-t));
    tout[bs] = t;
  }
}

// ---------------- global stats -> twn; also emits scale_temps output ----------------
__global__ __launch_bounds__(256) void stats_k(const float* __restrict__ t0,
                                               const float* __restrict__ t1,
                                               const float* __restrict__ t2,
                                               float* __restrict__ twn,
                                               float* __restrict__ out2) {
  __shared__ float sh[4];
  const int tid = threadIdx.x;
  float s = 0.f;
  for (int i = tid; i < BS_; i += 256) s += (t0[i] + t1[i] + t2[i]) * (1.f / 3.f);
  const float mu = bred_sum(s, sh) * (1.f / (float)BS_);
  float q = 0.f;
  for (int i = tid; i < BS_; i += 256) {
    float tw = (t0[i] + t1[i] + t2[i]) * (1.f / 3.f);
    float d = tw - mu;
    q += d * d;
  }
  const float var = bred_sum(q, sh) * (1.f / (float)BS_);
  const float stdu = sqrtf(var);
  const float inv = 1.f / (stdu + 1.1920929e-07f);
  for (int i = tid; i < BS_; i += 256) {
    float tw = (t0[i] + t1[i] + t2[i]) * (1.f / 3.f);
    twn[i] = 1.f + (tw - mu) * inv;
  }
  for (int i = tid; i < 3 * BS_; i += 256) {  // [B,3,S,1]
    int b = i / 3072, r = i - b * 3072;
    int j = r >> 10, ss = r & 1023;
    const float* tp = (j == 0) ? t0 : ((j == 1) ? t1 : t2);
    out2[i] = tp[b * S_ + ss];
  }
}

// =====================================================================
extern "C" void kernel_launch(void* const* d_in, const int* in_sizes, int n_in,
                              void* d_out, int out_size, void* d_ws, size_t ws_size,
                              hipStream_t stream) {
  (void)in_sizes; (void)n_in; (void)out_size; (void)ws_size;
  const float* x     = (const float*)d_in[0];
  const float* wq    = (const float*)d_in[1];
  const float* wk    = (const float*)d_in[2];
  const float* wv    = (const float*)d_in[3];
  const float* wo    = (const float*)d_in[4];
  const float* w_in  = (const float*)d_in[5];
  const float* w_out = (const float*)d_in[6];
  const float* wt    = (const float*)d_in[7];
  const float* ttm_g = (const float*)d_in[8];
  const float* ttm_b = (const float*)d_in[9];
  const float* thp_w = (const float*)d_in[10];
  const float* thp_b = (const float*)d_in[11];
  const float* thp_g = (const float*)d_in[12];
  const float* thp_e = (const float*)d_in[13];
  const float* w1    = (const float*)d_in[14];
  const float* b1    = (const float*)d_in[15];
  const float* tn_g  = (const float*)d_in[16];
  const float* tn_e  = (const float*)d_in[17];
  const float* w2    = (const float*)d_in[18];
  const float* b2    = (const float*)d_in[19];

  char* ws = (char*)d_ws;
  size_t off = 0;
  auto alloc = [&](size_t bytes) {
    void* p = ws + off;
    off = (off + bytes + 255) & ~(size_t)255;
    return p;
  };

  __hip_bfloat16* xb    = (__hip_bfloat16*)alloc((size_t)BS_ * H_ * 2);
  __hip_bfloat16* winb  = (__hip_bfloat16*)alloc((size_t)H3_ * H_ * 2);
  __hip_bfloat16* woutb = (__hip_bfloat16*)alloc((size_t)H_ * H_ * 2);
  __hip_bfloat16* wqkvb = (__hip_bfloat16*)alloc((size_t)H3_ * H_ * 2);
  __hip_bfloat16* wob   = (__hip_bfloat16*)alloc((size_t)H_ * H_ * 2);
  __hip_bfloat16* wtpb  = (__hip_bfloat16*)alloc((size_t)128 * H_ * 2);
  __hip_bfloat16* w1b   = (__hip_bfloat16*)alloc((size_t)H_ * 2 * H_ * 2);
  __hip_bfloat16* qkvb  = (__hip_bfloat16*)alloc((size_t)BS_ * H3_ * 2);
  __hip_bfloat16* vtb   = (__hip_bfloat16*)alloc((size_t)64 * DH_ * S_ * 2);
  __hip_bfloat16* mctxb = (__hip_bfloat16*)alloc((size_t)BS_ * H_ * 2);
  __hip_bfloat16* tob   = (__hip_bfloat16*)alloc((size_t)BS_ * H_ * 2);
  float* wtp   = (float*)alloc((size_t)BS_ * 128 * 4);
  float* T0    = (float*)alloc((size_t)BS_ * NH_ * 4);
  float* xw1a  = (float*)alloc((size_t)BS_ * H_ * 4);
  float* tbw   = (float*)alloc((size_t)BS_ * H_ * 4);
  float* temps = (float*)alloc((size_t)3 * BS_ * 4);
  float* twn   = (float*)alloc((size_t)BS_ * 4);
  float* rsum  = (float*)alloc((size_t)H_ * 4);

  const float scale = 0.125f;  // DH^-0.5
  dim3 blk(256);

  // ---- casts ----
  cast_k<<<(BS_ * H_ + 255) / 256, blk, 0, stream>>>(x, xb, BS_ * H_);
  cast_k<<<(H3_ * H_ + 255) / 256, blk, 0, stream>>>(w_in, winb, H3_ * H_);
  cast_k<<<(H_ * H_ + 255) / 256, blk, 0, stream>>>(w_out, woutb, H_ * H_);
  cast_k<<<(H_ * H_ + 255) / 256, blk, 0, stream>>>(wq, wqkvb, H_ * H_);
  cast_k<<<(H_ * H_ + 255) / 256, blk, 0, stream>>>(wk, wqkvb + (size_t)H_ * H_, H_ * H_);
  cast_k<<<(H_ * H_ + 255) / 256, blk, 0, stream>>>(wv, wqkvb + (size_t)2 * H_ * H_, H_ * H_);
  cast_k<<<(H_ * H_ + 255) / 256, blk, 0, stream>>>(wo, wob, H_ * H_);
  cast_pad_k<<<(128 * H_ + 255) / 256, blk, 0, stream>>>(wt, wtpb, NH_ * H_, 128 * H_);
  cast_k<<<(H_ * 2 * H_ + 255) / 256, blk, 0, stream>>>(w1, w1b, H_ * 2 * H_);

  // ---- ttm MHA ----
  gemm_bt<4, 4, 2, 2, true><<<dim3(H3_ / 128, BS_ / 128, 1), blk, 0, stream>>>(
      xb, winb, qkvb, H_, H_, H_, H3_, 0, 0, 0);
  transpose_v_k<<<dim3(S_ / 64, 64), blk, 0, stream>>>(qkvb, vtb);
  flash_k<true><<<dim3(8, 64), blk, 0, stream>>>(qkvb, vtb, (const float*)nullptr, mctxb, scale);
  gemm_bt<4, 4, 2, 2, true><<<dim3(H_ / 128, BS_ / 128, 1), blk, 0, stream>>>(
      mctxb, woutb, tob, H_, H_, H_, H_, 0, 0, 0);
  gemm_bt<4, 4, 2, 2, false><<<dim3(1, BS_ / 128, 1), blk, 0, stream>>>(
      tob, wtpb, wtp, H_, H_, H_, 128, 0, 0, 0);
  ttm_temp_k<<<BS_ / 256, blk, 0, stream>>>(wtp, ttm_g, ttm_b, T0);
  thp_k<<<BS_, blk, 0, stream>>>(T0, thp_w, thp_b, thp_g, thp_e, tob, temps);

  // ---- temp_net (algebraic split of comb @ W1^T) ----
  gemm_bt<4, 4, 2, 2, false><<<dim3(H_ / 128, BS_ / 128, 1), blk, 0, stream>>>(
      xb, w1b, xw1a, H_, H_, 2 * H_, H_, 0, 0, 0);
  gemm_bt<4, 4, 2, 2, false><<<dim3(H_ / 128, BS_ / 128, 1), blk, 0, stream>>>(
      tob, w1b + H_, tbw, H_, H_, 2 * H_, H_, 0, 0, 0);
  rowsum_k<<<H_ / 4, blk, 0, stream>>>(w1, rsum);
  hln_k<<<BS_, blk, 0, stream>>>(xw1a, tbw, (const float*)nullptr, rsum, b1, tn_g, tn_e, tbw, 0);
  rowdot_k<<<BS_, blk, 0, stream>>>(tbw, w2, b2, temps + BS_);
  hln_k<<<BS_, blk, 0, stream>>>(xw1a, tbw, temps + BS_, rsum, b1, tn_g, tn_e, tbw, 1);
  rowdot_k<<<BS_, blk, 0, stream>>>(tbw, w2, b2, temps + 2 * BS_);
  stats_k<<<1, blk, 0, stream>>>(temps, temps + BS_, temps + 2 * BS_, twn,
                                 (float*)d_out + (size_t)BS_ * H_);

  // ---- main attention ----
  gemm_bt<4, 4, 2, 2, true><<<dim3(H3_ / 128, BS_ / 128, 1), blk, 0, stream>>>(
      xb, wqkvb, qkvb, H_, H_, H_, H3_, 0, 0, 0);
  transpose_v_k<<<dim3(S_ / 64, 64), blk, 0, stream>>>(qkvb, vtb);
  flash_k<false><<<dim3(8, 64), blk, 0, stream>>>(qkvb, vtb, twn, mctxb, scale);
  gemm_bt<4, 4, 2, 2, false><<<dim3(H_ / 128, BS_ / 128, 1), blk, 0, stream>>>(
      mctxb, wob, (float*)d_out, H_, H_, H_, H_, 0, 0, 0);
}